// Round 2
// baseline (593.970 us; speedup 1.0000x reference)
//
#include <hip/hip_runtime.h>
#include <hip/hip_bf16.h>
#include <math.h>

// Problem: B=128 rows, D=512*512=262144. dots[i][j] = X[i]·Y[j] (fp32),
// sim[j][i] = dots[i][j]/max(|X_i||Y_j|,eps); top1/top10 retrieval accuracy.
//
// Main kernel: split-K GEMM, 512 blocks each own K-chunk of 512.
// Block = 256 threads (16x16), each thread accumulates an 8x8 tile of the
// full 128x128 C. Norms (sum of squares) fused into the staging loads.
// Cross-block reduce via global fp32 atomicAdd into d_ws (64 KB needed).

#define DIMD 262144
#define NBLK 512
#define KC   512      // DIMD / NBLK
#define BK   16
#define LSTR 132      // LDS row stride: mult of 4 (16B-aligned float4) + bank rotation

__global__ __launch_bounds__(256)
void dot_norm_kernel(const float* __restrict__ Z, const float* __restrict__ Y,
                     float* __restrict__ dots, float* __restrict__ norms) {
    __shared__ float lA[BK][LSTR];
    __shared__ float lB[BK][LSTR];

    const int tid = threadIdx.x;
    const int tx = tid & 15;
    const int ty = tid >> 4;
    const int r0 = ty * 8;
    const int c0 = tx * 8;
    const int rowm = tid >> 2;     // 0..63 (slot0 row; slot1 = rowm+64)
    const int kq   = tid & 3;      // which float4 within BK=16

    float acc[8][8];
#pragma unroll
    for (int i = 0; i < 8; ++i)
#pragma unroll
        for (int j = 0; j < 8; ++j) acc[i][j] = 0.f;

    float a2s0 = 0.f, a2s1 = 0.f, b2s0 = 0.f, b2s1 = 0.f;

    const size_t kbase = (size_t)blockIdx.x * KC;
    const size_t offA0 = (size_t)rowm * DIMD + kbase + kq * 4;
    const size_t offA1 = (size_t)(rowm + 64) * DIMD + kbase + kq * 4;

#pragma unroll 1
    for (int t = 0; t < KC / BK; ++t) {
        const size_t ko = (size_t)t * BK;
        const float4 av0 = *(const float4*)(Z + offA0 + ko);
        const float4 av1 = *(const float4*)(Z + offA1 + ko);
        const float4 bv0 = *(const float4*)(Y + offA0 + ko);
        const float4 bv1 = *(const float4*)(Y + offA1 + ko);

        a2s0 += av0.x*av0.x + av0.y*av0.y + av0.z*av0.z + av0.w*av0.w;
        a2s1 += av1.x*av1.x + av1.y*av1.y + av1.z*av1.z + av1.w*av1.w;
        b2s0 += bv0.x*bv0.x + bv0.y*bv0.y + bv0.z*bv0.z + bv0.w*bv0.w;
        b2s1 += bv1.x*bv1.x + bv1.y*bv1.y + bv1.z*bv1.z + bv1.w*bv1.w;

        __syncthreads();   // previous tile's compute finished
        const int kk = kq * 4;
        lA[kk+0][rowm]    = av0.x; lA[kk+1][rowm]    = av0.y;
        lA[kk+2][rowm]    = av0.z; lA[kk+3][rowm]    = av0.w;
        lA[kk+0][rowm+64] = av1.x; lA[kk+1][rowm+64] = av1.y;
        lA[kk+2][rowm+64] = av1.z; lA[kk+3][rowm+64] = av1.w;
        lB[kk+0][rowm]    = bv0.x; lB[kk+1][rowm]    = bv0.y;
        lB[kk+2][rowm]    = bv0.z; lB[kk+3][rowm]    = bv0.w;
        lB[kk+0][rowm+64] = bv1.x; lB[kk+1][rowm+64] = bv1.y;
        lB[kk+2][rowm+64] = bv1.z; lB[kk+3][rowm+64] = bv1.w;
        __syncthreads();

#pragma unroll
        for (int k = 0; k < BK; ++k) {
            const float4 a0 = *(const float4*)&lA[k][r0];
            const float4 a1 = *(const float4*)&lA[k][r0 + 4];
            const float4 b0 = *(const float4*)&lB[k][c0];
            const float4 b1 = *(const float4*)&lB[k][c0 + 4];
            const float a[8] = {a0.x,a0.y,a0.z,a0.w,a1.x,a1.y,a1.z,a1.w};
            const float b[8] = {b0.x,b0.y,b0.z,b0.w,b1.x,b1.y,b1.z,b1.w};
#pragma unroll
            for (int i = 0; i < 8; ++i)
#pragma unroll
                for (int j = 0; j < 8; ++j)
                    acc[i][j] = fmaf(a[i], b[j], acc[i][j]);
        }
    }

    // ---- norms: block-level LDS reduce, then one global atomic per thread
    __syncthreads();
    float* nrm = &lA[0][0];           // reuse LDS, 256 floats
    nrm[tid] = 0.f;
    __syncthreads();
    atomicAdd(&nrm[rowm],        a2s0);
    atomicAdd(&nrm[rowm + 64],   a2s1);
    atomicAdd(&nrm[128 + rowm],      b2s0);
    atomicAdd(&nrm[128 + rowm + 64], b2s1);
    __syncthreads();
    atomicAdd(&norms[tid], nrm[tid]);

    // ---- dots: cross-block atomic reduce
#pragma unroll
    for (int i = 0; i < 8; ++i)
#pragma unroll
        for (int j = 0; j < 8; ++j)
            atomicAdd(&dots[(size_t)(r0 + i) * 128 + (c0 + j)], acc[i][j]);
}

// sim[a][b] = dots[b][a] / max(xn[b]*yn[a], eps); per-row ranking of diag.
__global__ void finalize_kernel(const float* __restrict__ dots,
                                const float* __restrict__ norms,
                                float* __restrict__ out) {
    __shared__ int c1, c10;
    const int a = threadIdx.x;     // 128 threads, row index (Y side)
    if (a == 0) { c1 = 0; c10 = 0; }
    __syncthreads();

    const float yna = sqrtf(norms[128 + a]);
    const float va  = dots[(size_t)a * 128 + a] / fmaxf(sqrtf(norms[a]) * yna, 1e-8f);
    int cnt = 0;
    for (int b = 0; b < 128; ++b) {
        const float vb = dots[(size_t)b * 128 + a] / fmaxf(sqrtf(norms[b]) * yna, 1e-8f);
        cnt += (b != a && vb > va) ? 1 : 0;
    }
    atomicAdd(&c1,  (cnt == 0) ? 1 : 0);
    atomicAdd(&c10, (cnt < 10) ? 1 : 0);
    __syncthreads();
    if (a == 0) {
        out[0] = (float)c1  / 128.0f;
        out[1] = (float)c10 / 128.0f;
    }
}

extern "C" void kernel_launch(void* const* d_in, const int* in_sizes, int n_in,
                              void* d_out, int out_size, void* d_ws, size_t ws_size,
                              hipStream_t stream) {
    const float* Z = (const float*)d_in[0];
    const float* Y = (const float*)d_in[1];
    float* dots  = (float*)d_ws;          // 128*128 fp32 accumulators
    float* norms = dots + 128 * 128;      // 128 xn2 then 128 yn2
    float* out   = (float*)d_out;

    // ws is re-poisoned to 0xAA before every call — zero the accumulators.
    hipMemsetAsync(d_ws, 0, (128 * 128 + 256) * sizeof(float), stream);

    dot_norm_kernel<<<NBLK, 256, 0, stream>>>(Z, Y, dots, norms);
    finalize_kernel<<<1, 128, 0, stream>>>(dots, norms, out);
}